// Round 3
// baseline (480.564 us; speedup 1.0000x reference)
//
#include <hip/hip_runtime.h>

#define NTYPES 100
#define EMBED 64
#define N_BATCH 9000
#define ATOMS_PER_MOL 64
#define N_ATOMS (N_BATCH * ATOMS_PER_MOL)   // 576000
#define TOTAL4 (N_ATOMS * 16)               // 9,216,000 float4 outputs
#define GRID 1024                           // 4 blocks/CU x 256 CUs -> co-resident
#define BLOCK 256
#define NTHREADS (GRID * BLOCK)

// Single fused kernel: mark presence -> grid barrier -> rank scan -> gather.
//
// Co-residency: __launch_bounds__(256,4) guarantees >=4 waves/SIMD capacity
// (= 4 blocks/CU of 256 threads); grid is exactly 4*256 CUs, so all 1024
// blocks are resident and the atomic barrier cannot deadlock. Spin is bounded
// as a belt-and-suspenders hang guard.
//
// Cross-XCD coherence: presence marks use agent-scope atomic stores/loads and
// the barrier uses __threadfence() release/acquire, so marks written on one
// XCD are visible to readers on another (per-XCD L2s are not coherent for
// plain cached accesses within a single kernel).
__global__ __launch_bounds__(BLOCK, 4) void ae_fused(
        const int* __restrict__ atom_types,
        const float4* __restrict__ emb4,
        int* __restrict__ present,
        int* __restrict__ bar,
        float4* __restrict__ out4) {
    const int tid = threadIdx.x;
    const int gid = blockIdx.x * BLOCK + tid;

    // ---- Phase 1: presence marking (int4 load, 4 agent-scope flag stores) ----
    const int n4 = N_ATOMS / 4;  // 144000 < NTHREADS -> single pass
    if (gid < n4) {
        int4 v = ((const int4*)atom_types)[gid];
        __hip_atomic_store(&present[v.x], 1, __ATOMIC_RELAXED, __HIP_MEMORY_SCOPE_AGENT);
        __hip_atomic_store(&present[v.y], 1, __ATOMIC_RELAXED, __HIP_MEMORY_SCOPE_AGENT);
        __hip_atomic_store(&present[v.z], 1, __ATOMIC_RELAXED, __HIP_MEMORY_SCOPE_AGENT);
        __hip_atomic_store(&present[v.w], 1, __ATOMIC_RELAXED, __HIP_MEMORY_SCOPE_AGENT);
    }

    // ---- Phase 2: grid barrier (arrive + spin, thread 0 per block) ----
    __syncthreads();
    if (tid == 0) {
        __threadfence();              // release: flush marks to coherent point
        atomicAdd(bar, 1);            // device-scope
        long long guard = 0;
        while (__hip_atomic_load(bar, __ATOMIC_RELAXED, __HIP_MEMORY_SCOPE_AGENT) < GRID) {
            __builtin_amdgcn_s_sleep(2);
            if (++guard > (100LL * 1000 * 1000)) break;  // hang guard (~seconds)
        }
        __threadfence();              // acquire: see other blocks' marks
    }
    __syncthreads();

    // ---- Phase 3: rank[t] = #present types < t (exclusive scan in LDS) ----
    __shared__ int s_present[NTYPES];
    __shared__ int s_rank[NTYPES];
    if (tid < NTYPES)
        s_present[tid] = __hip_atomic_load(&present[tid], __ATOMIC_RELAXED,
                                           __HIP_MEMORY_SCOPE_AGENT);
    __syncthreads();
    if (tid < NTYPES) {
        int r = 0;
        for (int j = 0; j < tid; ++j) r += s_present[j];
        s_rank[tid] = r;
    }
    __syncthreads();

    // ---- Phase 4: gather. 16 threads/atom, float4 coalesced stores. ----
    for (int g = gid; g < TOTAL4; g += NTHREADS) {
        int t = atom_types[g >> 4];          // broadcast within 16-lane group
        out4[g] = emb4[s_rank[t] * 16 + (g & 15)];  // L1-resident table read
    }
}

extern "C" void kernel_launch(void* const* d_in, const int* in_sizes, int n_in,
                              void* d_out, int out_size, void* d_ws, size_t ws_size,
                              hipStream_t stream) {
    const int* atom_types  = (const int*)d_in[0];    // [9000,64] int32
    const float* embedding = (const float*)d_in[1];  // [100,64]  f32
    float* out             = (float*)d_out;          // [9000,64,64] f32

    // ws layout: [0,512) present[128] ; [512,516) barrier counter
    int* present = (int*)d_ws;
    int* bar     = (int*)((char*)d_ws + 512);

    // Node 0: zero presence flags + barrier counter (ws is poisoned 0xAA and
    // never re-poisoned between replays).
    hipMemsetAsync(d_ws, 0, 1024, stream);

    // Node 1: the whole op.
    ae_fused<<<GRID, BLOCK, 0, stream>>>(atom_types, (const float4*)embedding,
                                         present, bar, (float4*)out);
}

// Round 4
// 69.122 us; speedup vs baseline: 6.9524x; 6.9524x over previous
//
#include <hip/hip_runtime.h>

#define NTYPES 100
#define EMBED 64
#define N_BATCH 9000
#define ATOMS_PER_MOL 64
#define N_ATOMS (N_BATCH * ATOMS_PER_MOL)   // 576000
#define TOTAL4 (N_ATOMS * 16)               // 9,216,000 float4 outputs
#define GRID 1024                           // 4 blocks/CU x 256 CUs -> co-resident
#define BLOCK 256
#define NTHREADS (GRID * BLOCK)
#define MARKERS 64                          // blocks that scan atom_types

// Single fused kernel. R3 post-mortem: the 480us was 576K agent-scope atomic
// stores serializing at the coherent point (~25 lines), NOT the barrier.
// This version reduces coherent-point RMWs to ~324 total:
//   - 64 marker blocks scan atom_types into per-thread register bitmaps
//     (4 x u32 covers types 0..127), wave shfl_xor OR-reduce, LDS combine,
//     then 4 global atomicOr per block + 1 arrive atomicAdd.
//   - all 1024 blocks spin on arrive==64 (s_sleep, bounded guard), then
//     compute rank[t] = popcount(bitmap bits < t) into an LDS LUT, then
//     gather with fully-coalesced float4 stores.
// Co-residency: __launch_bounds__(256,4) + grid = 4*256CUs; R3 measured
// occupancy 48% (=16/32 waves/CU) confirming the full grid is resident, so
// non-marker blocks spinning cannot starve markers.
__global__ __launch_bounds__(BLOCK, 4) void ae_fused(
        const int* __restrict__ atom_types,
        const float4* __restrict__ emb4,
        unsigned* __restrict__ bitmap,   // 4 words, zeroed by memset node
        int* __restrict__ arrive,        // zeroed by memset node
        float4* __restrict__ out4) {
    const int tid = threadIdx.x;
    __shared__ unsigned s_bm[4];
    __shared__ int s_rank[NTYPES];

    // ---- Phase 1 (marker blocks only): presence bitmap ----
    if (blockIdx.x < MARKERS) {
        if (tid < 4) s_bm[tid] = 0u;
        __syncthreads();
        unsigned b0 = 0, b1 = 0, b2 = 0, b3 = 0;
        const int4* at4 = (const int4*)atom_types;
        const int n4 = N_ATOMS / 4;  // 144000 -> ~9 int4 per thread
        for (int i = blockIdx.x * BLOCK + tid; i < n4; i += MARKERS * BLOCK) {
            int4 v = at4[i];
#define AE_SETBIT(t) { unsigned m = 1u << ((t) & 31); int j = (t) >> 5; \
            if (j == 0) b0 |= m; else if (j == 1) b1 |= m; \
            else if (j == 2) b2 |= m; else b3 |= m; }
            AE_SETBIT(v.x); AE_SETBIT(v.y); AE_SETBIT(v.z); AE_SETBIT(v.w);
#undef AE_SETBIT
        }
        // wave-level OR butterfly (64 lanes)
        for (int off = 32; off >= 1; off >>= 1) {
            b0 |= __shfl_xor(b0, off);
            b1 |= __shfl_xor(b1, off);
            b2 |= __shfl_xor(b2, off);
            b3 |= __shfl_xor(b3, off);
        }
        if ((tid & 63) == 0) {        // lane 0 of each of 4 waves
            atomicOr(&s_bm[0], b0);
            atomicOr(&s_bm[1], b1);
            atomicOr(&s_bm[2], b2);
            atomicOr(&s_bm[3], b3);
        }
        __syncthreads();
        if (tid < 4 && s_bm[tid]) atomicOr(&bitmap[tid], s_bm[tid]);  // device-scope RMW
        __syncthreads();              // vmcnt(0) drain: block's ORs are at coherent point
        if (tid == 0) {
            __threadfence();          // release
            atomicAdd(arrive, 1);     // device-scope
        }
    }

    // ---- Phase 2: wait for all markers, publish bitmap to LDS ----
    if (tid == 0) {
        long long guard = 0;
        while (__hip_atomic_load(arrive, __ATOMIC_RELAXED,
                                 __HIP_MEMORY_SCOPE_AGENT) < MARKERS) {
            __builtin_amdgcn_s_sleep(8);
            if (++guard > 4000000LL) break;   // hang guard (~0.5 s worst case)
        }
        __threadfence();              // acquire
        s_bm[0] = __hip_atomic_load(&bitmap[0], __ATOMIC_RELAXED, __HIP_MEMORY_SCOPE_AGENT);
        s_bm[1] = __hip_atomic_load(&bitmap[1], __ATOMIC_RELAXED, __HIP_MEMORY_SCOPE_AGENT);
        s_bm[2] = __hip_atomic_load(&bitmap[2], __ATOMIC_RELAXED, __HIP_MEMORY_SCOPE_AGENT);
        s_bm[3] = __hip_atomic_load(&bitmap[3], __ATOMIC_RELAXED, __HIP_MEMORY_SCOPE_AGENT);
    }
    __syncthreads();

    // ---- Phase 3: rank LUT. rank[t] = # set bits strictly below t ----
    if (tid < NTYPES) {
        int j = tid >> 5, b = tid & 31;
        int r = __popc(s_bm[j] & ((1u << b) - 1u));
        for (int k = 0; k < j; ++k) r += __popc(s_bm[k]);
        s_rank[tid] = r;
    }
    __syncthreads();

    // ---- Phase 4: gather. 16 threads/atom, coalesced 16B/lane stores ----
    for (int g = blockIdx.x * BLOCK + tid; g < TOTAL4; g += NTHREADS) {
        int t = atom_types[g >> 4];             // 4 distinct addrs/wave, broadcast
        out4[g] = emb4[s_rank[t] * 16 + (g & 15)];  // 25.6 KB table, L1-resident
    }
}

extern "C" void kernel_launch(void* const* d_in, const int* in_sizes, int n_in,
                              void* d_out, int out_size, void* d_ws, size_t ws_size,
                              hipStream_t stream) {
    const int* atom_types  = (const int*)d_in[0];    // [9000,64] int32
    const float* embedding = (const float*)d_in[1];  // [100,64]  f32
    float* out             = (float*)d_out;          // [9000,64,64] f32

    // ws layout: [0,16) bitmap[4] ; [16,20) arrive counter
    unsigned* bitmap = (unsigned*)d_ws;
    int* arrive      = (int*)((char*)d_ws + 16);

    // Node 0: zero bitmap + arrive (ws is poisoned 0xAA and never re-poisoned
    // between replays; arrive also accumulates +64 per call without this).
    hipMemsetAsync(d_ws, 0, 64, stream);

    // Node 1: the whole op.
    ae_fused<<<GRID, BLOCK, 0, stream>>>(atom_types, (const float4*)embedding,
                                         bitmap, arrive, (float4*)out);
}